// Round 3
// baseline (13385.930 us; speedup 1.0000x reference)
//
#include <hip/hip_runtime.h>
#include <hip/hip_bf16.h>

#define TT 2048
#define BB 32
#define DD 256
#define HH 512
#define NWG 32      // workgroups per layer
#define UPW 16      // hidden units per workgroup
#define RING 64     // h ring depth (power of 2)

typedef unsigned long long u64;
typedef unsigned u32;
using f32x4 = __attribute__((ext_vector_type(4))) float;
using s16x8 = __attribute__((ext_vector_type(8))) short;

// Tagged h rings: each 8B word = [h_even | h_odd<<16 | epoch<<32].
// 8B relaxed agent atomics are single-copy atomic -> data+validity in one
// store; NO flags, NO producer-side waitcnt, NO fences on the step path.
__device__ __attribute__((aligned(16))) u64 g_r0[RING][BB][HH / 2];
__device__ __attribute__((aligned(16))) u64 g_r1[RING][BB][HH / 2];
__device__ __attribute__((aligned(16))) __hip_bfloat16 g_xb[BB][TT][DD];  // x pre-cast to bf16
__device__ __attribute__((aligned(16))) float g_h1f[BB][HH];
__device__ int g_prog1;  // L1 progress (throttles L0 vs ring depth)

__device__ __forceinline__ short f2bf(float f) {
    union { float f; unsigned u; } v; v.f = f;
    unsigned r = v.u + 0x7fffu + ((v.u >> 16) & 1u);  // RNE
    return (short)(r >> 16);
}
__device__ __forceinline__ float sigm(float x) { return 1.f / (1.f + __expf(-x)); }
__device__ __forceinline__ float tanh_f(float x) { return 1.f - 2.f / (__expf(2.f * x) + 1.f); }

// ---------------------------------------------------------------------------
// Persistent per-layer scan. wave = (m-tile, K-quarter); weights in VGPRs.
// Per step: [stage w/ tag-retry] barrier [MFMA + gbuf] barrier [ew + publish].
// ---------------------------------------------------------------------------
template <int LAYER>
__device__ void scan_layer(char* smem, int wgk,
                           const float* __restrict__ Wih, const float* __restrict__ Whh,
                           const float* __restrict__ bih, const float* __restrict__ bhh) {
    constexpr int KIN = (LAYER == 0) ? DD : HH;  // 256 / 512
    constexpr int KL  = KIN + HH;                // 768 / 1024
    constexpr int QK  = KL / 4;                  // K per wave-quarter
    constexpr int NKQ = QK / 32;                 // MFMA k-steps per quarter
    constexpr int NGR = KL / 128;                // stage groups per thread (8 vals each)
    constexpr int NXG = (LAYER == 0) ? 2 : 0;    // x groups
    constexpr int NHG = NGR - NXG;               // tagged h groups (4 / 8)
    constexpr int ROWB = 2048;                   // LDS A row stride (bytes)

    const int tid  = threadIdx.x;
    const int wave = tid >> 6;
    const int lane = tid & 63;
    const int m    = wave & 1;   // M tile (batch 16-half)
    const int q    = wave >> 1;  // K quarter
    const int u16i = lane & 15;
    const int hi   = lane >> 4;

    // ---- Load weight fragments into registers (one-time) ------------------
    s16x8 wreg[NKQ * 4];
    {
        const int unit = wgk * UPW + u16i;
#pragma unroll
        for (int ks = 0; ks < NKQ; ++ks) {
#pragma unroll
            for (int gt = 0; gt < 4; ++gt) {
                const int k = q * QK + ks * 32 + hi * 8;
                const float* src = (k < KIN)
                    ? (Wih + (size_t)(gt * HH + unit) * KIN + k)
                    : (Whh + (size_t)(gt * HH + unit) * HH + (k - KIN));
                s16x8 w;
#pragma unroll
                for (int j = 0; j < 8; ++j) w[j] = f2bf(src[j]);
                wreg[ks * 4 + gt] = w;
            }
        }
    }

    // ---- Elementwise thread mapping: (batch, unit) owned per thread --------
    const int eb = tid >> 4;
    const int eu = tid & 15;
    const int unit_g = wgk * UPW + eu;
    float bias[4];
#pragma unroll
    for (int gt = 0; gt < 4; ++gt)
        bias[gt] = bih[gt * HH + unit_g] + bhh[gt * HH + unit_g];
    float c = 0.f;

    // ---- Stage thread mapping ---------------------------------------------
    const int sb = tid >> 4;   // batch row this thread stages
    const int sk = tid & 15;   // group column

    float* gbuf = (float*)(smem + 65536);  // DISJOINT from A region

    for (int t = 0; t < TT; ++t) {
        // ---- 0. L0 ring-overwrite throttle (rare, off critical path) ------
        if (LAYER == 0 && (t & 15) == 0) {
            int it = 0;
            while (__hip_atomic_load(&g_prog1, __ATOMIC_RELAXED, __HIP_MEMORY_SCOPE_AGENT) < t - 32) {
                if (++it > (1 << 20)) break;
            }
        }

        // ---- 1. Stage x groups (plain bf16 16B loads, L2-cached) ----------
        if (LAYER == 0) {
#pragma unroll
            for (int g = 0; g < NXG; ++g) {
                const int kg = sk + 16 * g;
                s16x8 v = *(const s16x8*)&g_xb[sb][t][kg * 8];
                *(s16x8*)(smem + sb * ROWB + ((kg * 16) ^ ((sb & 7) << 4))) = v;
            }
        }

        // ---- 2. Stage h groups: tagged loads, issue-all-then-retry --------
        u64 hw[NHG][4];
        const u64* hp[NHG];
        u32 expv[NHG];
#pragma unroll
        for (int g = 0; g < NHG; ++g) {
            const int k = (sk + 16 * (g + NXG)) * 8;
            if (LAYER == 0) {
                hp[g] = &g_r0[t & (RING - 1)][sb][(k - DD) / 2];
                expv[g] = (u32)t;
            } else if (g < 4) {
                hp[g] = &g_r0[(t + 1) & (RING - 1)][sb][k / 2];
                expv[g] = (u32)(t + 1);
            } else {
                hp[g] = &g_r1[t & (RING - 1)][sb][(k - HH) / 2];
                expv[g] = (u32)t;
            }
        }
#pragma unroll
        for (int g = 0; g < NHG; ++g)
#pragma unroll
            for (int j = 0; j < 4; ++j)
                hw[g][j] = __hip_atomic_load(hp[g] + j, __ATOMIC_RELAXED, __HIP_MEMORY_SCOPE_AGENT);
        {
            int it = 0;
            for (;;) {
                u32 bad = 0;
#pragma unroll
                for (int g = 0; g < NHG; ++g)
#pragma unroll
                    for (int j = 0; j < 4; ++j)
                        if ((u32)(hw[g][j] >> 32) != expv[g]) bad |= (1u << (g * 4 + j));
                if (!bad) break;
                if (++it > (1 << 15)) break;  // escape: wrong answer beats hang
#pragma unroll
                for (int g = 0; g < NHG; ++g)
#pragma unroll
                    for (int j = 0; j < 4; ++j)
                        if (bad & (1u << (g * 4 + j)))
                            hw[g][j] = __hip_atomic_load(hp[g] + j, __ATOMIC_RELAXED, __HIP_MEMORY_SCOPE_AGENT);
            }
        }
#pragma unroll
        for (int g = 0; g < NHG; ++g) {
            const int kg = sk + 16 * (g + NXG);
            s16x8 v;
#pragma unroll
            for (int j = 0; j < 4; ++j) {
                v[2 * j]     = (short)(u32)hw[g][j];
                v[2 * j + 1] = (short)((u32)hw[g][j] >> 16);
            }
            *(s16x8*)(smem + sb * ROWB + ((kg * 16) ^ ((sb & 7) << 4))) = v;
        }

        __syncthreads();  // (b) A tile complete

        // ---- 3. MFMA: 4 gate tiles per wave, A read once per k-step --------
        f32x4 acc[4] = {{0,0,0,0},{0,0,0,0},{0,0,0,0},{0,0,0,0}};
        {
            const int arow = m * 16 + u16i;
            const char* abase = smem + arow * ROWB;
            const int aswz = (arow & 7) << 4;
#pragma unroll
            for (int ks = 0; ks < NKQ; ++ks) {
                const int off = (q * QK + ks * 32 + hi * 8) * 2;
                s16x8 a = *(const s16x8*)(abase + (off ^ aswz));
#pragma unroll
                for (int gt = 0; gt < 4; ++gt)
                    acc[gt] = __builtin_amdgcn_mfma_f32_16x16x32_bf16(a, wreg[ks * 4 + gt], acc[gt], 0, 0, 0);
            }
        }

        // ---- 4. K-quarter partials -> gbuf (disjoint region, no barrier) ---
#pragma unroll
        for (int gt = 0; gt < 4; ++gt) {
#pragma unroll
            for (int r = 0; r < 4; ++r) {
                const int b = m * 16 + hi * 4 + r;  // C row = (lane>>4)*4 + reg
                gbuf[(q * BB + b) * 68 + gt * 16 + u16i] = acc[gt][r];
            }
        }

        __syncthreads();  // (e) partials complete

        // ---- 5. Gate elementwise + tagged publish (fire-and-forget) --------
        {
            float gv[4];
#pragma unroll
            for (int gt = 0; gt < 4; ++gt) {
                float s = bias[gt];
#pragma unroll
                for (int qq = 0; qq < 4; ++qq) s += gbuf[(qq * BB + eb) * 68 + gt * 16 + eu];
                gv[gt] = s;
            }
            const float ig = sigm(gv[0]);
            const float fg = sigm(gv[1]);
            const float gg = tanh_f(gv[2]);
            const float og = sigm(gv[3]);
            c = fg * c + ig * gg;
            const float h = og * tanh_f(c);
            const u32 hu = (u32)(unsigned short)f2bf(h);
            const u32 other = __shfl_xor(hu, 1);
            if (LAYER == 1 && t == TT - 1) g_h1f[eb][unit_g] = h;
            if ((eu & 1) == 0) {
                const u64 w = (u64)(hu | (other << 16)) | ((u64)(u32)(t + 1) << 32);
                u64* dst = (LAYER == 0)
                    ? &g_r0[(t + 1) & (RING - 1)][eb][unit_g / 2]
                    : &g_r1[(t + 1) & (RING - 1)][eb][unit_g / 2];
                __hip_atomic_store(dst, w, __ATOMIC_RELAXED, __HIP_MEMORY_SCOPE_AGENT);
            }
            if (LAYER == 1 && wgk == 0 && tid == 0)
                __hip_atomic_store(&g_prog1, t + 1, __ATOMIC_RELAXED, __HIP_MEMORY_SCOPE_AGENT);
        }
        // no barrier here: next stage writes A (dead since (e)); gbuf reads
        // above are ordered vs next iter's gbuf writes by barrier (b).
    }
}

__global__ __launch_bounds__(512, 2) void lstm_scan(
    const float* __restrict__ Wih0, const float* __restrict__ Whh0,
    const float* __restrict__ bih0, const float* __restrict__ bhh0,
    const float* __restrict__ Wih1, const float* __restrict__ Whh1,
    const float* __restrict__ bih1, const float* __restrict__ bhh1) {
    __shared__ __attribute__((aligned(16))) char smem[65536 + 4 * BB * 68 * 4];
    const int layer = blockIdx.x >> 5;
    const int wgk   = blockIdx.x & (NWG - 1);
    if (layer == 0) scan_layer<0>(smem, wgk, Wih0, Whh0, bih0, bhh0);
    else            scan_layer<1>(smem, wgk, Wih1, Whh1, bih1, bhh1);
}

// prep: zero rings + progress (wgs 0..63) and cast x -> bf16 (wgs 64..).
__global__ void prep_kernel(const float* __restrict__ x) {
    const int wg = blockIdx.x;
    const int tid = threadIdx.x;
    if (wg < 64) {
        ulonglong2* base = (ulonglong2*)((wg < 32) ? &g_r0[0][0][0] : &g_r1[0][0][0]);
        const int per = (RING * BB * (HH / 2)) / 2 / 32;  // 8192 ulonglong2 per wg
        ulonglong2* p = base + (size_t)(wg & 31) * per;
        const ulonglong2 z = {0ull, 0ull};
        for (int i = tid; i < per; i += 256) p[i] = z;
        if (wg == 0 && tid == 0) g_prog1 = 0;
    } else {
        const size_t i = (size_t)(wg - 64) * 256 + tid;  // one 8-float group
        const float4* xs = (const float4*)x + i * 2;
        const float4 a = xs[0], b = xs[1];
        s16x8 v;
        v[0] = f2bf(a.x); v[1] = f2bf(a.y); v[2] = f2bf(a.z); v[3] = f2bf(a.w);
        v[4] = f2bf(b.x); v[5] = f2bf(b.y); v[6] = f2bf(b.z); v[7] = f2bf(b.w);
        ((s16x8*)&g_xb[0][0][0])[i] = v;
    }
}

__global__ void out_kernel(const float* __restrict__ Wout, const float* __restrict__ bout,
                           float* __restrict__ out) {
    const int b = blockIdx.x;
    const int o = threadIdx.x;
    const float4* h4 = (const float4*)&g_h1f[b][0];
    const float4* w4 = (const float4*)(Wout + (size_t)o * HH);
    float s = bout[o];
    for (int k = 0; k < HH / 4; ++k) {
        const float4 a = h4[k], w = w4[k];
        s += a.x * w.x + a.y * w.y + a.z * w.z + a.w * w.w;
    }
    out[b * 256 + o] = s;
}

extern "C" void kernel_launch(void* const* d_in, const int* in_sizes, int n_in,
                              void* d_out, int out_size, void* d_ws, size_t ws_size,
                              hipStream_t stream) {
    const float* x    = (const float*)d_in[0];
    const float* Wih0 = (const float*)d_in[1];
    const float* Whh0 = (const float*)d_in[2];
    const float* bih0 = (const float*)d_in[3];
    const float* bhh0 = (const float*)d_in[4];
    const float* Wih1 = (const float*)d_in[5];
    const float* Whh1 = (const float*)d_in[6];
    const float* bih1 = (const float*)d_in[7];
    const float* bhh1 = (const float*)d_in[8];
    const float* Wout = (const float*)d_in[9];
    const float* bout = (const float*)d_in[10];
    float* out = (float*)d_out;

    // x groups: 32*2048*256/8 = 2,097,152 -> 8192 wgs of 256; +64 reset wgs
    hipLaunchKernelGGL(prep_kernel, dim3(64 + 8192), dim3(256), 0, stream, x);
    hipLaunchKernelGGL(lstm_scan, dim3(2 * NWG), dim3(512), 0, stream,
                       Wih0, Whh0, bih0, bhh0, Wih1, Whh1, bih1, bhh1);
    hipLaunchKernelGGL(out_kernel, dim3(BB), dim3(256), 0, stream, Wout, bout, out);
}